// Round 7
// baseline (182.761 us; speedup 1.0000x reference)
//
#include <hip/hip_runtime.h>
#include <hip/hip_bf16.h>
#include <stddef.h>
#include <stdint.h>

typedef __bf16 bf16_t;
typedef bf16_t bf16x8 __attribute__((ext_vector_type(8)));
typedef bf16_t bf16x4 __attribute__((ext_vector_type(4)));
typedef bf16_t bf16x2 __attribute__((ext_vector_type(2)));
typedef float floatx4 __attribute__((ext_vector_type(4)));
typedef float floatx16 __attribute__((ext_vector_type(16)));
typedef int   intx4  __attribute__((ext_vector_type(4)));

#define SEQ    4096
#define DMODEL 512
#define NH     8
#define BATCH  2
#define QSCALE 0.18033688011112042f   /* 2^-3 * log2(e): folded into Q so P=exp2(S') */

// async global->LDS, 16B per lane; LDS dest = wave-uniform base + lane*16
__device__ __forceinline__ void ld_lds16(const void* g, void* l) {
  __builtin_amdgcn_global_load_lds(
      (const __attribute__((address_space(1))) unsigned int*)g,
      (__attribute__((address_space(3))) unsigned int*)l, 16, 0, 0);
}

// ---------------------------------------------------------------------------
// prep: z<4 -> Wt[z][n][k] = (bf16)W_z[k][n]; z==4 -> xb = (bf16)x
// ---------------------------------------------------------------------------
__global__ __launch_bounds__(256) void prep_k(
    const float* __restrict__ x,
    const float* __restrict__ W0, const float* __restrict__ W1,
    const float* __restrict__ W2, const float* __restrict__ W3,
    bf16_t* __restrict__ Wt, bf16_t* __restrict__ xb)
{
  if (blockIdx.z == 4) {
    const floatx4* xf = (const floatx4*)x;
    bf16x4* xo = (bf16x4*)xb;
    int base = (blockIdx.y * 16 + blockIdx.x) * 4096 + threadIdx.x;
    #pragma unroll
    for (int i = 0; i < 16; i++) {
      floatx4 v = xf[base + i * 256];
      xo[base + i * 256] = bf16x4{(bf16_t)v.x, (bf16_t)v.y, (bf16_t)v.z, (bf16_t)v.w};
    }
    return;
  }
  __shared__ float Ws[32][33];
  const float* W = (blockIdx.z == 0) ? W0 : (blockIdx.z == 1) ? W1
                 : (blockIdx.z == 2) ? W2 : W3;
  bf16_t* out = Wt + (size_t)blockIdx.z * DMODEL * DMODEL;
  const int tx = threadIdx.x & 31, ty = threadIdx.x >> 5;
  const int k0 = blockIdx.y * 32, n0 = blockIdx.x * 32;
  #pragma unroll
  for (int i = 0; i < 4; i++) {
    int kk = ty + i * 8;
    Ws[kk][tx] = W[(size_t)(k0 + kk) * DMODEL + n0 + tx];
  }
  __syncthreads();
  #pragma unroll
  for (int i = 0; i < 4; i++) {
    int nn = ty + i * 8;
    out[(size_t)(n0 + nn) * DMODEL + k0 + tx] = (bf16_t)Ws[tx][nn];
  }
}

// ---------------------------------------------------------------------------
// QKV GEMM, BK=32 (16 iters), tile 128x128. blockIdx.y: mode=y>>2, hp=y&3.
// Modes 0(Q),1(K) OPERAND-SWAPPED: A=W-slab (M=W-cols), B=x-slab (N=rows).
// C-layout then gives each lane 4 CONSECUTIVE output-cols -> bf16x4 stores,
// no LDS epilogue. Mode 2(V) unswapped: lane holds 4 consecutive tokens at
// fixed d -> direct sigma-permuted bf16x4 stores into [d][tok] tiles.
// LDS: A 8KB + B 8KB per buf, dbuf 32KB -> 3 blocks/CU on 768-block grid.
// 16B-chunk XOR swizzle (4 chunks/row, cc = b ^ (r&3)) -> 2-way alias only.
// ---------------------------------------------------------------------------
__global__ __launch_bounds__(256) void qkv_k(
    const bf16_t* __restrict__ xb, const bf16_t* __restrict__ Wt,
    bf16_t* __restrict__ Qw, bf16_t* __restrict__ Ksw, bf16_t* __restrict__ Vsw)
{
  __shared__ __align__(16) char smem[2 * 16384];   // 32 KB
  const int tid  = threadIdx.x;
  const int wave = tid >> 6;
  const int lane = tid & 63;
  const int lh   = lane >> 4, lm = lane & 15;
  const int bx   = blockIdx.x;
  const int mode = blockIdx.y >> 2;
  const int hp   = blockIdx.y & 3;
  const bf16_t* Wm = Wt + (size_t)mode * DMODEL * DMODEL;
  const bool SW  = (mode != 2);
  const bf16_t* srcA = SW ? (Wm + (size_t)hp * 128 * DMODEL)
                          : (xb + (size_t)bx * 128 * DMODEL);
  const bf16_t* srcB = SW ? (xb + (size_t)bx * 128 * DMODEL)
                          : (Wm + (size_t)hp * 128 * DMODEL);

  // staging: 512 16B-chunks per matrix per buf; chunk S -> row S>>2, slot S&3
  int offR[2], ldsO[2];
  #pragma unroll
  for (int i = 0; i < 2; i++) {
    int S = i * 256 + tid;
    int r = S >> 2, bc = S & 3, cc = bc ^ (r & 3);
    offR[i] = r * DMODEL + cc * 8;
    ldsO[i] = (i * 256 + wave * 64) * 16;
  }

  floatx4 acc[2][8];
  #pragma unroll
  for (int rb = 0; rb < 2; rb++)
    #pragma unroll
    for (int nb = 0; nb < 8; nb++) acc[rb][nb] = floatx4{0.f, 0.f, 0.f, 0.f};

  auto issue = [&](int kt, int buf) {
    char* bp = smem + buf * 16384;
    #pragma unroll
    for (int i = 0; i < 2; i++) {
      ld_lds16(srcA + offR[i] + kt * 32, bp + ldsO[i]);
      ld_lds16(srcB + offR[i] + kt * 32, bp + 8192 + ldsO[i]);
    }
  };

  issue(0, 0);
  for (int kt = 0; kt < 16; kt++) {
    __syncthreads();
    if (kt < 15) issue(kt + 1, (kt + 1) & 1);
    const char* bp = smem + (kt & 1) * 16384;
    int rA = wave * 32 + lm;
    bf16x8 a0 = *(const bf16x8*)(bp + (rA * 4 + (lh ^ (rA & 3))) * 16);
    bf16x8 a1 = *(const bf16x8*)(bp + ((rA + 16) * 4 + (lh ^ (rA & 3))) * 16);
    #pragma unroll
    for (int nb = 0; nb < 8; nb++) {
      int n = nb * 16 + lm;
      bf16x8 b = *(const bf16x8*)(bp + 8192 + (n * 4 + (lh ^ (n & 3))) * 16);
      acc[0][nb] = __builtin_amdgcn_mfma_f32_16x16x32_bf16(a0, b, acc[0][nb], 0, 0, 0);
      acc[1][nb] = __builtin_amdgcn_mfma_f32_16x16x32_bf16(a1, b, acc[1][nb], 0, 0, 0);
    }
  }

  if (mode == 0) {
    // Q: swapped -> lane holds 4 consecutive cols at fixed qrow
    #pragma unroll
    for (int rb = 0; rb < 2; rb++)
      #pragma unroll
      for (int nb = 0; nb < 8; nb++) {
        int col0 = hp * 128 + wave * 32 + rb * 16 + lh * 4;
        int qrow = bx * 128 + nb * 16 + lm;
        bf16x4 v = {(bf16_t)(acc[rb][nb][0] * QSCALE), (bf16_t)(acc[rb][nb][1] * QSCALE),
                    (bf16_t)(acc[rb][nb][2] * QSCALE), (bf16_t)(acc[rb][nb][3] * QSCALE)};
        *(bf16x4*)&Qw[(size_t)qrow * DMODEL + col0] = v;
      }
  } else if (mode == 1) {
    // K: swapped -> 4 consecutive d at fixed key; swizzled [key][d] tiles
    #pragma unroll
    for (int rb = 0; rb < 2; rb++)
      #pragma unroll
      for (int nb = 0; nb < 8; nb++) {
        int d0g = hp * 128 + wave * 32 + rb * 16 + lh * 4;
        int h = d0g >> 6, dl = d0g & 63;
        int key = bx * 128 + nb * 16 + lm;
        int bb = key >> 12, tk = key & 4095;
        size_t off = ((size_t)(bb * NH + h) * 64 + (tk >> 6)) * 4096
                   + (size_t)(tk & 63) * 64
                   + (((dl >> 3) ^ (tk & 7)) << 3) + (dl & 7);
        bf16x4 v = {(bf16_t)acc[rb][nb][0], (bf16_t)acc[rb][nb][1],
                    (bf16_t)acc[rb][nb][2], (bf16_t)acc[rb][nb][3]};
        *(bf16x4*)&Ksw[off] = v;
      }
  } else {
    // V: unswapped -> 4 consecutive tokens at fixed d; sigma + swizzle
    #pragma unroll
    for (int rb = 0; rb < 2; rb++)
      #pragma unroll
      for (int nb = 0; nb < 8; nb++) {
        int t0 = bx * 128 + wave * 32 + rb * 16 + lh * 4;   // global token
        int bb = t0 >> 12, tt = t0 & 4095, tin = tt & 63;
        int pos = (tin & ~15) | (((tin >> 2) & 1) << 3) | (((tin >> 3) & 1) << 2);
        int colg = hp * 128 + nb * 16 + lm;
        int h = colg >> 6, d = colg & 63;
        size_t off = ((size_t)(bb * NH + h) * 64 + (tt >> 6)) * 4096
                   + (size_t)d * 64
                   + (((pos >> 3) ^ (d & 7)) << 3) + (pos & 7);
        bf16x4 v = {(bf16_t)acc[rb][nb][0], (bf16_t)acc[rb][nb][1],
                    (bf16_t)acc[rb][nb][2], (bf16_t)acc[rb][nb][3]};
        *(bf16x4*)&Vsw[off] = v;
      }
  }
}

// ---------------------------------------------------------------------------
// O-projection: out[8192,512] fp32 = Ow bf16 @ Wt3^T + bias.
// Tile 128x64, BK=32 (16 iters), dbuf 24KB.
// ---------------------------------------------------------------------------
__global__ __launch_bounds__(256) void out_k(
    const bf16_t* __restrict__ A, const bf16_t* __restrict__ Wt,
    const float* __restrict__ bias, float* __restrict__ out)
{
  __shared__ __align__(16) char smem[2 * 12288];   // 24 KB
  const int tid  = threadIdx.x;
  const int wave = tid >> 6;
  const int lane = tid & 63;
  const int lh   = lane >> 4, lm = lane & 15;
  const int bm   = blockIdx.x * 128;
  const int bn   = blockIdx.y * 64;

  int offRA[2], ldsOA[2];
  #pragma unroll
  for (int i = 0; i < 2; i++) {
    int S = i * 256 + tid;
    int r = S >> 2, bc = S & 3, cc = bc ^ (r & 3);
    offRA[i] = (bm + r) * DMODEL + cc * 8;
    ldsOA[i] = (i * 256 + wave * 64) * 16;
  }
  int offB, ldsOB;
  {
    int S = tid;                       // 256 chunks: 64 rows x 4
    int n = S >> 2, bc = S & 3, cc = bc ^ (n & 3);
    offB  = (bn + n) * DMODEL + cc * 8;
    ldsOB = (512 + wave * 64) * 16;
  }

  floatx4 acc[2][4];
  #pragma unroll
  for (int rb = 0; rb < 2; rb++)
    #pragma unroll
    for (int nb = 0; nb < 4; nb++) acc[rb][nb] = floatx4{0.f, 0.f, 0.f, 0.f};

  auto issue = [&](int kt, int buf) {
    char* bp = smem + buf * 12288;
    #pragma unroll
    for (int i = 0; i < 2; i++) ld_lds16(A + offRA[i] + kt * 32, bp + ldsOA[i]);
    ld_lds16(Wt + offB + kt * 32, bp + ldsOB);
  };

  issue(0, 0);
  for (int kt = 0; kt < 16; kt++) {
    __syncthreads();
    if (kt < 15) issue(kt + 1, (kt + 1) & 1);
    const char* bp = smem + (kt & 1) * 12288;
    int rA = wave * 32 + lm;
    bf16x8 a0 = *(const bf16x8*)(bp + (rA * 4 + (lh ^ (rA & 3))) * 16);
    bf16x8 a1 = *(const bf16x8*)(bp + ((rA + 16) * 4 + (lh ^ (rA & 3))) * 16);
    #pragma unroll
    for (int nb = 0; nb < 4; nb++) {
      int n = nb * 16 + lm;
      bf16x8 b = *(const bf16x8*)(bp + (512 + n * 4 + (lh ^ (n & 3))) * 16);
      acc[0][nb] = __builtin_amdgcn_mfma_f32_16x16x32_bf16(a0, b, acc[0][nb], 0, 0, 0);
      acc[1][nb] = __builtin_amdgcn_mfma_f32_16x16x32_bf16(a1, b, acc[1][nb], 0, 0, 0);
    }
  }

  #pragma unroll
  for (int rb = 0; rb < 2; rb++)
    #pragma unroll
    for (int nb = 0; nb < 4; nb++) {
      float bv = bias[bn + nb * 16 + lm];
      #pragma unroll
      for (int r = 0; r < 4; r++) {
        int row = bm + wave * 32 + rb * 16 + lh * 4 + r;
        out[(size_t)row * DMODEL + bn + nb * 16 + lm] = acc[rb][nb][r] + bv;
      }
    }
}

// ---------------------------------------------------------------------------
// Flash attention (r6 structure): 512 thr = 8 waves (4 qh x 2 kh), 128 q,
// dbuf 64KB KV staging, sigma'd V => P B-frags from own regs, max-free
// softmax. Changed: merge slabs padded to stride-20 floats (bank spread).
// ---------------------------------------------------------------------------
__global__ __launch_bounds__(512, 4) void attn_k(
    const bf16_t* __restrict__ Qw, const bf16_t* __restrict__ Ksw,
    const bf16_t* __restrict__ Vsw, bf16_t* __restrict__ Ow)
{
  __shared__ __align__(16) char smem[2 * 32768];   // 64 KB
  const int tid  = threadIdx.x;
  const int wave = tid >> 6;
  const int qh   = wave >> 1;
  const int kh   = wave & 1;
  const int lane = tid & 63;
  const int hi   = lane >> 5;
  const int lo   = lane & 31;
  const int bh   = blockIdx.y, b = bh >> 3, h = bh & 7;
  const int q0   = blockIdx.x * 128;
  const size_t kvbase = (size_t)bh * 64 * 4096;

  const int qrow_g = b * SEQ + q0 + qh * 32 + lo;
  bf16x8 qreg[4];
  #pragma unroll
  for (int i = 0; i < 4; i++)
    qreg[i] = *(const bf16x8*)&Qw[(size_t)qrow_g * DMODEL + h * 64 + i * 16 + hi * 8];

  floatx16 accO[2];
  #pragma unroll
  for (int nbo = 0; nbo < 2; nbo++)
    #pragma unroll
    for (int j = 0; j < 16; j++) accO[nbo][j] = 0.f;
  float ls = 0.f;

  auto issue = [&](int s, int buf) {
    char* bp = smem + buf * 32768;
    const bf16_t* k0 = Ksw + kvbase + (size_t)(2 * s) * 4096;
    const bf16_t* v0 = Vsw + kvbase + (size_t)(2 * s) * 4096;
    ld_lds16(k0 + tid * 8,        bp + tid * 16);
    ld_lds16(v0 + tid * 8,        bp + 8192 + tid * 16);
    ld_lds16(k0 + 4096 + tid * 8, bp + 16384 + tid * 16);
    ld_lds16(v0 + 4096 + tid * 8, bp + 24576 + tid * 16);
  };

  issue(0, 0);
  for (int s = 0; s < SEQ / 128; s++) {
    __syncthreads();
    if (s < SEQ / 128 - 1) issue(s + 1, (s + 1) & 1);
    const bf16_t* Kb = (const bf16_t*)(smem + (s & 1) * 32768 + kh * 16384);
    const bf16_t* Vb = Kb + 4096;

    floatx16 accS[2];
    #pragma unroll
    for (int nb = 0; nb < 2; nb++)
      #pragma unroll
      for (int j = 0; j < 16; j++) accS[nb][j] = 0.f;
    #pragma unroll
    for (int kd = 0; kd < 4; kd++) {
      #pragma unroll
      for (int nb = 0; nb < 2; nb++) {
        int row = nb * 32 + lo;
        bf16x8 ak = *(const bf16x8*)&Kb[row * 64 + (((kd * 2 + hi) ^ (row & 7)) << 3)];
        accS[nb] = __builtin_amdgcn_mfma_f32_32x32x16_bf16(ak, qreg[kd], accS[nb], 0, 0, 0);
      }
    }

    int pk[2][8];
    #pragma unroll
    for (int nb = 0; nb < 2; nb++) {
      float p[16];
      #pragma unroll
      for (int r = 0; r < 16; r++) p[r] = __builtin_amdgcn_exp2f(accS[nb][r]);
      #pragma unroll
      for (int r = 0; r < 16; r += 4)
        ls += (p[r] + p[r + 1]) + (p[r + 2] + p[r + 3]);
      #pragma unroll
      for (int i = 0; i < 8; i++) {
        bf16x2 t2 = {(bf16_t)p[2 * i], (bf16_t)p[2 * i + 1]};
        pk[nb][i] = __builtin_bit_cast(int, t2);
      }
    }

    #pragma unroll
    for (int c = 0; c < 4; c++) {
      intx4 pi = {pk[c >> 1][4 * (c & 1)],     pk[c >> 1][4 * (c & 1) + 1],
                  pk[c >> 1][4 * (c & 1) + 2], pk[c >> 1][4 * (c & 1) + 3]};
      bf16x8 pf = __builtin_bit_cast(bf16x8, pi);
      #pragma unroll
      for (int nbo = 0; nbo < 2; nbo++) {
        int row = nbo * 32 + lo;
        bf16x8 av = *(const bf16x8*)&Vb[row * 64 + (((c * 2 + hi) ^ (row & 7)) << 3)];
        accO[nbo] = __builtin_amdgcn_mfma_f32_32x32x16_bf16(av, pf, accO[nbo], 0, 0, 0);
      }
    }
  }

  // ---- merge kh pairs; padded slabs (stride 20 floats -> 8 bank-groups) ----
  ls += __shfl_xor(ls, 32, 64);
  __syncthreads();
  float* mrg = (float*)smem;
  if (kh == 1) {
    #pragma unroll
    for (int nbo = 0; nbo < 2; nbo++) {
      float* dst = mrg + qh * 2720 + nbo * 1360 + lane * 20;
      #pragma unroll
      for (int g = 0; g < 4; g++) {
        dst[4 * g + 0] = accO[nbo][4 * g + 0];
        dst[4 * g + 1] = accO[nbo][4 * g + 1];
        dst[4 * g + 2] = accO[nbo][4 * g + 2];
        dst[4 * g + 3] = accO[nbo][4 * g + 3];
      }
    }
    if (hi == 0) mrg[10816 + qh * 32 + lo] = ls;
  }
  __syncthreads();
  if (kh == 0) {
    float linv = 1.0f / (ls + mrg[10816 + qh * 32 + lo]);
    #pragma unroll
    for (int nbo = 0; nbo < 2; nbo++) {
      const float* src = mrg + qh * 2720 + nbo * 1360 + lane * 20;
      #pragma unroll
      for (int g = 0; g < 4; g++) {
        accO[nbo][4 * g + 0] += src[4 * g + 0];
        accO[nbo][4 * g + 1] += src[4 * g + 1];
        accO[nbo][4 * g + 2] += src[4 * g + 2];
        accO[nbo][4 * g + 3] += src[4 * g + 3];
      }
    }
    bf16_t* Os = (bf16_t*)(smem + 49152 + qh * 4096);   // [32 q][64 d]
    #pragma unroll
    for (int nbo = 0; nbo < 2; nbo++)
      #pragma unroll
      for (int g = 0; g < 4; g++) {
        int dbase = g * 8 + 4 * hi + 32 * nbo;
        bf16x4 v4 = {(bf16_t)(accO[nbo][4 * g] * linv),
                     (bf16_t)(accO[nbo][4 * g + 1] * linv),
                     (bf16_t)(accO[nbo][4 * g + 2] * linv),
                     (bf16_t)(accO[nbo][4 * g + 3] * linv)};
        *(bf16x4*)&Os[lo * 64 + (dbase ^ ((lo & 7) << 3))] = v4;
      }
    #pragma unroll
    for (int i = 0; i < 4; i++) {
      int idx = i * 64 + lane;
      int q = idx >> 3, c8 = idx & 7;
      bf16x8 v = *(const bf16x8*)&Os[q * 64 + ((c8 ^ (q & 7)) << 3)];
      int row_g = b * SEQ + q0 + qh * 32 + q;
      *(bf16x8*)&Ow[(size_t)row_g * DMODEL + h * 64 + c8 * 8] = v;
    }
  }
}

// ---------------------------------------------------------------------------
extern "C" void kernel_launch(void* const* d_in, const int* in_sizes, int n_in,
                              void* d_out, int out_size, void* d_ws, size_t ws_size,
                              hipStream_t stream)
{
  const float* x  = (const float*)d_in[0];
  const float* Wq = (const float*)d_in[1];
  const float* Wk = (const float*)d_in[2];
  const float* Wv = (const float*)d_in[3];
  const float* Wo = (const float*)d_in[4];
  const float* bo = (const float*)d_in[5];
  float* out = (float*)d_out;

  const int M = BATCH * SEQ;                     // 8192
  const size_t WT = (size_t)DMODEL * DMODEL;     // 262144
  const size_t E  = (size_t)M * DMODEL;          // 4,194,304
  if (ws_size < (4 * WT + 3 * E) * sizeof(bf16_t)) return;   // 26 MB

  bf16_t* Wt  = (bf16_t*)d_ws;
  bf16_t* Qw  = Wt + 4 * WT;
  bf16_t* Ksw = Qw + E;
  bf16_t* Vsw = Ksw + E;
  bf16_t* Ow  = Qw;             // alias: attn reads its Q rows before writing O
  bf16_t* xbf = (bf16_t*)d_out; // d_out's first 8MB as scratch: dead by out_k

  prep_k<<<dim3(16, 16, 5), 256, 0, stream>>>(x, Wq, Wk, Wv, Wo, Wt, xbf);

  qkv_k<<<dim3(M / 128, 12), 256, 0, stream>>>(xbf, Wt, Qw, Ksw, Vsw);

  attn_k<<<dim3(SEQ / 128, BATCH * NH), 512, 0, stream>>>(Qw, Ksw, Vsw, Ow);

  out_k<<<dim3(M / 128, DMODEL / 64), 256, 0, stream>>>(Ow, Wt + 3 * WT, bo, out);
}

// Round 8
// 172.332 us; speedup vs baseline: 1.0605x; 1.0605x over previous
//
#include <hip/hip_runtime.h>
#include <hip/hip_bf16.h>
#include <stddef.h>
#include <stdint.h>

typedef __bf16 bf16_t;
typedef bf16_t bf16x8 __attribute__((ext_vector_type(8)));
typedef bf16_t bf16x4 __attribute__((ext_vector_type(4)));
typedef bf16_t bf16x2 __attribute__((ext_vector_type(2)));
typedef float floatx4 __attribute__((ext_vector_type(4)));
typedef float floatx16 __attribute__((ext_vector_type(16)));
typedef int   intx4  __attribute__((ext_vector_type(4)));

#define SEQ    4096
#define DMODEL 512
#define NH     8
#define BATCH  2
#define QSCALE 0.18033688011112042f   /* 2^-3 * log2(e): folded into Q so P=exp2(S') */

// async global->LDS, 16B per lane; LDS dest = wave-uniform base + lane*16
__device__ __forceinline__ void ld_lds16(const void* g, void* l) {
  __builtin_amdgcn_global_load_lds(
      (const __attribute__((address_space(1))) unsigned int*)g,
      (__attribute__((address_space(3))) unsigned int*)l, 16, 0, 0);
}

// ---------------------------------------------------------------------------
// prep: z<4 -> Wt[z][n][k] = (bf16)W_z[k][n]; z==4 -> xb = (bf16)x
// ---------------------------------------------------------------------------
__global__ __launch_bounds__(256) void prep_k(
    const float* __restrict__ x,
    const float* __restrict__ W0, const float* __restrict__ W1,
    const float* __restrict__ W2, const float* __restrict__ W3,
    bf16_t* __restrict__ Wt, bf16_t* __restrict__ xb)
{
  if (blockIdx.z == 4) {
    const floatx4* xf = (const floatx4*)x;
    bf16x4* xo = (bf16x4*)xb;
    int base = (blockIdx.y * 16 + blockIdx.x) * 4096 + threadIdx.x;
    #pragma unroll
    for (int i = 0; i < 16; i++) {
      floatx4 v = xf[base + i * 256];
      xo[base + i * 256] = bf16x4{(bf16_t)v.x, (bf16_t)v.y, (bf16_t)v.z, (bf16_t)v.w};
    }
    return;
  }
  __shared__ float Ws[32][33];
  const float* W = (blockIdx.z == 0) ? W0 : (blockIdx.z == 1) ? W1
                 : (blockIdx.z == 2) ? W2 : W3;
  bf16_t* out = Wt + (size_t)blockIdx.z * DMODEL * DMODEL;
  const int tx = threadIdx.x & 31, ty = threadIdx.x >> 5;
  const int k0 = blockIdx.y * 32, n0 = blockIdx.x * 32;
  #pragma unroll
  for (int i = 0; i < 4; i++) {
    int kk = ty + i * 8;
    Ws[kk][tx] = W[(size_t)(k0 + kk) * DMODEL + n0 + tx];
  }
  __syncthreads();
  #pragma unroll
  for (int i = 0; i < 4; i++) {
    int nn = ty + i * 8;
    out[(size_t)(n0 + nn) * DMODEL + k0 + tx] = (bf16_t)Ws[tx][nn];
  }
}

// ---------------------------------------------------------------------------
// Fused QKV GEMM (r4 structure, measured-best non-attn). A = xb [8192x512],
// Wt = 3 mats [n][k]. Tile 128(M) x 32(N per matrix) x 64(K); one A-staging
// feeds 3 B-slabs (24 MFMA/iter/wave). LDS per buf: A 16KB + 3x4KB B = 28KB;
// dbuf 57344 B. XOR swizzle at 16B chunks baked into per-lane src addresses.
// Epilogues: Q natural *QSCALE; K swizzled [key][d] tiles; V LDS-transpose ->
// sigma-permuted swizzled [d][tok] tiles (r5/r6-verified store).
// ---------------------------------------------------------------------------
__global__ __launch_bounds__(256) void qkv_k(
    const bf16_t* __restrict__ xb, const bf16_t* __restrict__ Wt,
    bf16_t* __restrict__ Qw, bf16_t* __restrict__ Ksw, bf16_t* __restrict__ Vsw)
{
  __shared__ __align__(16) char smem[2 * 1792 * 16];   // 57344 B
  const int tid  = threadIdx.x;
  const int wave = tid >> 6;
  const int lane = tid & 63;
  const int lh   = lane >> 4, lm = lane & 15;
  const int bm   = blockIdx.x * 128;
  const int bn   = blockIdx.y * 32;

  int offA[4], ldsA[4];
  #pragma unroll
  for (int i = 0; i < 4; i++) {
    int S = i * 256 + wave * 64 + lane;
    int r = S >> 3, cc = (S & 7) ^ (r & 7);
    offA[i] = (bm + r) * DMODEL + cc * 8;
    ldsA[i] = (i * 256 + wave * 64) * 16;
  }
  int offB[3], ldsB[3];
  #pragma unroll
  for (int j = 0; j < 3; j++) {
    int S = j * 256 + wave * 64 + lane;
    int m = S >> 8, s2 = S & 255;
    int n = s2 >> 3, cc = (s2 & 7) ^ (n & 7);
    offB[j] = m * DMODEL * DMODEL + (bn + n) * DMODEL + cc * 8;
    ldsB[j] = (1024 + j * 256 + wave * 64) * 16;
  }

  floatx4 acc[3][2][2];
  #pragma unroll
  for (int m = 0; m < 3; m++)
    #pragma unroll
    for (int rb = 0; rb < 2; rb++)
      #pragma unroll
      for (int nb = 0; nb < 2; nb++)
        acc[m][rb][nb] = floatx4{0.f, 0.f, 0.f, 0.f};

  auto issue = [&](int kt, int buf) {
    char* bp = smem + buf * 1792 * 16;
    #pragma unroll
    for (int i = 0; i < 4; i++) ld_lds16(xb + offA[i] + kt * 64, bp + ldsA[i]);
    #pragma unroll
    for (int j = 0; j < 3; j++) ld_lds16(Wt + offB[j] + kt * 64, bp + ldsB[j]);
  };

  issue(0, 0);
  for (int kt = 0; kt < 8; kt++) {
    __syncthreads();                       // drains vmcnt: tile kt resident
    if (kt < 7) issue(kt + 1, (kt + 1) & 1);
    const char* bp = smem + (kt & 1) * 1792 * 16;
    #pragma unroll
    for (int ks = 0; ks < 2; ks++) {
      int cc = ks * 4 + lh;
      int rA = wave * 32 + lm;
      bf16x8 a0 = *(const bf16x8*)(bp + (rA * 8 + (cc ^ (rA & 7))) * 16);
      bf16x8 a1 = *(const bf16x8*)(bp + ((rA + 16) * 8 + (cc ^ (rA & 7))) * 16);
      #pragma unroll
      for (int m = 0; m < 3; m++) {
        #pragma unroll
        for (int nb = 0; nb < 2; nb++) {
          int n = nb * 16 + lm;
          bf16x8 b = *(const bf16x8*)(bp + (1024 + m * 256 + n * 8 + (cc ^ (n & 7))) * 16);
          acc[m][0][nb] = __builtin_amdgcn_mfma_f32_16x16x32_bf16(a0, b, acc[m][0][nb], 0, 0, 0);
          acc[m][1][nb] = __builtin_amdgcn_mfma_f32_16x16x32_bf16(a1, b, acc[m][1][nb], 0, 0, 0);
        }
      }
    }
  }

  const int h  = bn >> 6;           // head
  const int dl = bn & 63;           // d-offset of this 32-col slab in head
  // ---- Q: natural layout, pre-scaled ----
  #pragma unroll
  for (int rb = 0; rb < 2; rb++)
    #pragma unroll
    for (int nb = 0; nb < 2; nb++)
      #pragma unroll
      for (int r = 0; r < 4; r++) {
        int row = bm + wave * 32 + rb * 16 + lh * 4 + r;
        Qw[(size_t)row * DMODEL + bn + nb * 16 + lm] = (bf16_t)(acc[0][rb][nb][r] * QSCALE);
      }
  // ---- K: swizzled [64 key][64 d] tiles per (b,h) ----
  #pragma unroll
  for (int rb = 0; rb < 2; rb++)
    #pragma unroll
    for (int nb = 0; nb < 2; nb++) {
      int d = dl + nb * 16 + lm;
      #pragma unroll
      for (int r = 0; r < 4; r++) {
        int row = bm + wave * 32 + rb * 16 + lh * 4 + r;
        int bb = row >> 12, tk = row & 4095;
        size_t off = ((size_t)(bb * NH + h) * 64 + (tk >> 6)) * 4096
                   + (size_t)(tk & 63) * 64
                   + ((((d >> 3) ^ (tk & 7)) << 3) | (d & 7));
        Ksw[off] = (bf16_t)acc[1][rb][nb][r];
      }
    }
  // ---- V: LDS transpose -> sigma-permuted swizzled [64 d][64 tok] tiles ----
  bf16_t (*Ts)[136] = (bf16_t(*)[136])smem;   // 32 x 136 (buf0 region; safe)
  __syncthreads();
  #pragma unroll
  for (int rb = 0; rb < 2; rb++)
    #pragma unroll
    for (int nb = 0; nb < 2; nb++) {
      int dloc = nb * 16 + lm, tok0 = wave * 32 + rb * 16 + lh * 4;
      bf16x4 v = {(bf16_t)acc[2][rb][nb][0], (bf16_t)acc[2][rb][nb][1],
                  (bf16_t)acc[2][rb][nb][2], (bf16_t)acc[2][rb][nb][3]};
      *(bf16x4*)&Ts[dloc][tok0] = v;
    }
  __syncthreads();
  {
    const int bb = bm >> 12, tk0 = bm & 4095;
    const size_t hb = (size_t)(bb * NH + h) * 64;
    #pragma unroll
    for (int i = 0; i < 2; i++) {
      int idx = tid + i * 256;          // 0..511 : 32 d-rows x 16 chunks
      int dloc = idx >> 4, c8 = idx & 15;
      int d = dl + dloc;
      bf16x8 val = *(bf16x8*)&Ts[dloc][c8 * 8];
      int cw = c8 & 7;                  // chunk within 64-token tile
      int g = cw >> 1, sub = cw & 1;
      size_t tbase = (hb + (tk0 >> 6) + (c8 >> 3)) * 4096 + (size_t)d * 64;
      bf16x4 v0 = {val[0], val[1], val[2], val[3]};
      bf16x4 v1 = {val[4], val[5], val[6], val[7]};
      *(bf16x4*)&Vsw[tbase + (((2 * g) ^ (d & 7)) << 3) + sub * 4] = v0;
      *(bf16x4*)&Vsw[tbase + (((2 * g + 1) ^ (d & 7)) << 3) + sub * 4] = v1;
    }
  }
}

// ---------------------------------------------------------------------------
// O-projection GEMM (r6 version): out[8192,512] fp32 = Ow bf16 @ Wt3^T + bias.
// Tile 128x64x64, dbuf global_load_lds.
// ---------------------------------------------------------------------------
__global__ __launch_bounds__(256) void out_k(
    const bf16_t* __restrict__ A, const bf16_t* __restrict__ Wt,
    const float* __restrict__ bias, float* __restrict__ out)
{
  __shared__ __align__(16) char smem[2 * 1536 * 16];
  const int tid  = threadIdx.x;
  const int wave = tid >> 6;
  const int lane = tid & 63;
  const int lh   = lane >> 4, lm = lane & 15;
  const int bm   = blockIdx.x * 128;
  const int bn   = blockIdx.y * 64;

  int offA[4], ldsA[4];
  #pragma unroll
  for (int i = 0; i < 4; i++) {
    int S = i * 256 + wave * 64 + lane;
    int r = S >> 3, cc = (S & 7) ^ (r & 7);
    offA[i] = (bm + r) * DMODEL + cc * 8;
    ldsA[i] = (i * 256 + wave * 64) * 16;
  }
  int offB[2], ldsB[2];
  #pragma unroll
  for (int j = 0; j < 2; j++) {
    int S = j * 256 + wave * 64 + lane;
    int n = S >> 3, cc = (S & 7) ^ (n & 7);
    offB[j] = (bn + n) * DMODEL + cc * 8;
    ldsB[j] = (1024 + j * 256 + wave * 64) * 16;
  }

  floatx4 acc[2][4];
  #pragma unroll
  for (int rb = 0; rb < 2; rb++)
    #pragma unroll
    for (int nb = 0; nb < 4; nb++) acc[rb][nb] = floatx4{0.f, 0.f, 0.f, 0.f};

  auto issue = [&](int kt, int buf) {
    char* bp = smem + buf * 1536 * 16;
    #pragma unroll
    for (int i = 0; i < 4; i++) ld_lds16(A + offA[i] + kt * 64, bp + ldsA[i]);
    #pragma unroll
    for (int j = 0; j < 2; j++) ld_lds16(Wt + offB[j] + kt * 64, bp + ldsB[j]);
  };

  issue(0, 0);
  for (int kt = 0; kt < 8; kt++) {
    __syncthreads();
    if (kt < 7) issue(kt + 1, (kt + 1) & 1);
    const char* bp = smem + (kt & 1) * 1536 * 16;
    #pragma unroll
    for (int ks = 0; ks < 2; ks++) {
      int cc = ks * 4 + lh;
      int rA = wave * 32 + lm;
      bf16x8 a0 = *(const bf16x8*)(bp + (rA * 8 + (cc ^ (rA & 7))) * 16);
      bf16x8 a1 = *(const bf16x8*)(bp + ((rA + 16) * 8 + (cc ^ (rA & 7))) * 16);
      #pragma unroll
      for (int nb = 0; nb < 4; nb++) {
        int n = nb * 16 + lm;
        bf16x8 b = *(const bf16x8*)(bp + (1024 + n * 8 + (cc ^ (n & 7))) * 16);
        acc[0][nb] = __builtin_amdgcn_mfma_f32_16x16x32_bf16(a0, b, acc[0][nb], 0, 0, 0);
        acc[1][nb] = __builtin_amdgcn_mfma_f32_16x16x32_bf16(a1, b, acc[1][nb], 0, 0, 0);
      }
    }
  }

  #pragma unroll
  for (int rb = 0; rb < 2; rb++)
    #pragma unroll
    for (int nb = 0; nb < 4; nb++) {
      float bv = bias[bn + nb * 16 + lm];
      #pragma unroll
      for (int r = 0; r < 4; r++) {
        int row = bm + wave * 32 + rb * 16 + lh * 4 + r;
        out[(size_t)row * DMODEL + bn + nb * 16 + lm] = acc[rb][nb][r] + bv;
      }
    }
}

// ---------------------------------------------------------------------------
// Flash attention (r7 version): 512 thr = 8 waves (4 qh x 2 kh), 128 q,
// dbuf 64KB KV staging, sigma'd V => P B-frags from own regs, max-free
// softmax, padded merge slabs.
// ---------------------------------------------------------------------------
__global__ __launch_bounds__(512, 4) void attn_k(
    const bf16_t* __restrict__ Qw, const bf16_t* __restrict__ Ksw,
    const bf16_t* __restrict__ Vsw, bf16_t* __restrict__ Ow)
{
  __shared__ __align__(16) char smem[2 * 32768];   // 64 KB
  const int tid  = threadIdx.x;
  const int wave = tid >> 6;
  const int qh   = wave >> 1;
  const int kh   = wave & 1;
  const int lane = tid & 63;
  const int hi   = lane >> 5;
  const int lo   = lane & 31;
  const int bh   = blockIdx.y, b = bh >> 3, h = bh & 7;
  const int q0   = blockIdx.x * 128;
  const size_t kvbase = (size_t)bh * 64 * 4096;

  const int qrow_g = b * SEQ + q0 + qh * 32 + lo;
  bf16x8 qreg[4];
  #pragma unroll
  for (int i = 0; i < 4; i++)
    qreg[i] = *(const bf16x8*)&Qw[(size_t)qrow_g * DMODEL + h * 64 + i * 16 + hi * 8];

  floatx16 accO[2];
  #pragma unroll
  for (int nbo = 0; nbo < 2; nbo++)
    #pragma unroll
    for (int j = 0; j < 16; j++) accO[nbo][j] = 0.f;
  float ls = 0.f;

  auto issue = [&](int s, int buf) {
    char* bp = smem + buf * 32768;
    const bf16_t* k0 = Ksw + kvbase + (size_t)(2 * s) * 4096;
    const bf16_t* v0 = Vsw + kvbase + (size_t)(2 * s) * 4096;
    ld_lds16(k0 + tid * 8,        bp + tid * 16);
    ld_lds16(v0 + tid * 8,        bp + 8192 + tid * 16);
    ld_lds16(k0 + 4096 + tid * 8, bp + 16384 + tid * 16);
    ld_lds16(v0 + 4096 + tid * 8, bp + 24576 + tid * 16);
  };

  issue(0, 0);
  for (int s = 0; s < SEQ / 128; s++) {
    __syncthreads();
    if (s < SEQ / 128 - 1) issue(s + 1, (s + 1) & 1);
    const bf16_t* Kb = (const bf16_t*)(smem + (s & 1) * 32768 + kh * 16384);
    const bf16_t* Vb = Kb + 4096;

    floatx16 accS[2];
    #pragma unroll
    for (int nb = 0; nb < 2; nb++)
      #pragma unroll
      for (int j = 0; j < 16; j++) accS[nb][j] = 0.f;
    #pragma unroll
    for (int kd = 0; kd < 4; kd++) {
      #pragma unroll
      for (int nb = 0; nb < 2; nb++) {
        int row = nb * 32 + lo;
        bf16x8 ak = *(const bf16x8*)&Kb[row * 64 + (((kd * 2 + hi) ^ (row & 7)) << 3)];
        accS[nb] = __builtin_amdgcn_mfma_f32_32x32x16_bf16(ak, qreg[kd], accS[nb], 0, 0, 0);
      }
    }

    int pk[2][8];
    #pragma unroll
    for (int nb = 0; nb < 2; nb++) {
      float p[16];
      #pragma unroll
      for (int r = 0; r < 16; r++) p[r] = __builtin_amdgcn_exp2f(accS[nb][r]);
      #pragma unroll
      for (int r = 0; r < 16; r += 4)
        ls += (p[r] + p[r + 1]) + (p[r + 2] + p[r + 3]);
      #pragma unroll
      for (int i = 0; i < 8; i++) {
        bf16x2 t2 = {(bf16_t)p[2 * i], (bf16_t)p[2 * i + 1]};
        pk[nb][i] = __builtin_bit_cast(int, t2);
      }
    }

    #pragma unroll
    for (int c = 0; c < 4; c++) {
      intx4 pi = {pk[c >> 1][4 * (c & 1)],     pk[c >> 1][4 * (c & 1) + 1],
                  pk[c >> 1][4 * (c & 1) + 2], pk[c >> 1][4 * (c & 1) + 3]};
      bf16x8 pf = __builtin_bit_cast(bf16x8, pi);
      #pragma unroll
      for (int nbo = 0; nbo < 2; nbo++) {
        int row = nbo * 32 + lo;
        bf16x8 av = *(const bf16x8*)&Vb[row * 64 + (((c * 2 + hi) ^ (row & 7)) << 3)];
        accO[nbo] = __builtin_amdgcn_mfma_f32_32x32x16_bf16(av, pf, accO[nbo], 0, 0, 0);
      }
    }
  }

  // ---- merge kh pairs; padded slabs (stride 20 floats -> 8 bank-groups) ----
  ls += __shfl_xor(ls, 32, 64);
  __syncthreads();
  float* mrg = (float*)smem;
  if (kh == 1) {
    #pragma unroll
    for (int nbo = 0; nbo < 2; nbo++) {
      float* dst = mrg + qh * 2720 + nbo * 1360 + lane * 20;
      #pragma unroll
      for (int g = 0; g < 4; g++) {
        dst[4 * g + 0] = accO[nbo][4 * g + 0];
        dst[4 * g + 1] = accO[nbo][4 * g + 1];
        dst[4 * g + 2] = accO[nbo][4 * g + 2];
        dst[4 * g + 3] = accO[nbo][4 * g + 3];
      }
    }
    if (hi == 0) mrg[10816 + qh * 32 + lo] = ls;
  }
  __syncthreads();
  if (kh == 0) {
    float linv = 1.0f / (ls + mrg[10816 + qh * 32 + lo]);
    #pragma unroll
    for (int nbo = 0; nbo < 2; nbo++) {
      const float* src = mrg + qh * 2720 + nbo * 1360 + lane * 20;
      #pragma unroll
      for (int g = 0; g < 4; g++) {
        accO[nbo][4 * g + 0] += src[4 * g + 0];
        accO[nbo][4 * g + 1] += src[4 * g + 1];
        accO[nbo][4 * g + 2] += src[4 * g + 2];
        accO[nbo][4 * g + 3] += src[4 * g + 3];
      }
    }
    bf16_t* Os = (bf16_t*)(smem + 49152 + qh * 4096);   // [32 q][64 d]
    #pragma unroll
    for (int nbo = 0; nbo < 2; nbo++)
      #pragma unroll
      for (int g = 0; g < 4; g++) {
        int dbase = g * 8 + 4 * hi + 32 * nbo;
        bf16x4 v4 = {(bf16_t)(accO[nbo][4 * g] * linv),
                     (bf16_t)(accO[nbo][4 * g + 1] * linv),
                     (bf16_t)(accO[nbo][4 * g + 2] * linv),
                     (bf16_t)(accO[nbo][4 * g + 3] * linv)};
        *(bf16x4*)&Os[lo * 64 + (dbase ^ ((lo & 7) << 3))] = v4;
      }
    #pragma unroll
    for (int i = 0; i < 4; i++) {
      int idx = i * 64 + lane;
      int q = idx >> 3, c8 = idx & 7;
      bf16x8 v = *(const bf16x8*)&Os[q * 64 + ((c8 ^ (q & 7)) << 3)];
      int row_g = b * SEQ + q0 + qh * 32 + q;
      *(bf16x8*)&Ow[(size_t)row_g * DMODEL + h * 64 + c8 * 8] = v;
    }
  }
}

// ---------------------------------------------------------------------------
extern "C" void kernel_launch(void* const* d_in, const int* in_sizes, int n_in,
                              void* d_out, int out_size, void* d_ws, size_t ws_size,
                              hipStream_t stream)
{
  const float* x  = (const float*)d_in[0];
  const float* Wq = (const float*)d_in[1];
  const float* Wk = (const float*)d_in[2];
  const float* Wv = (const float*)d_in[3];
  const float* Wo = (const float*)d_in[4];
  const float* bo = (const float*)d_in[5];
  float* out = (float*)d_out;

  const int M = BATCH * SEQ;                     // 8192
  const size_t WT = (size_t)DMODEL * DMODEL;     // 262144
  const size_t E  = (size_t)M * DMODEL;          // 4,194,304
  if (ws_size < (4 * WT + 3 * E) * sizeof(bf16_t)) return;   // 26 MB

  bf16_t* Wt  = (bf16_t*)d_ws;
  bf16_t* Qw  = Wt + 4 * WT;
  bf16_t* Ksw = Qw + E;
  bf16_t* Vsw = Ksw + E;
  bf16_t* Ow  = Qw;             // alias: attn reads its Q rows before writing O
  bf16_t* xbf = (bf16_t*)d_out; // d_out's first 8MB as scratch: dead by out_k

  prep_k<<<dim3(16, 16, 5), 256, 0, stream>>>(x, Wq, Wk, Wv, Wo, Wt, xbf);

  qkv_k<<<dim3(M / 128, DMODEL / 32), 256, 0, stream>>>(xbf, Wt, Qw, Ksw, Vsw);

  attn_k<<<dim3(SEQ / 128, BATCH * NH), 512, 0, stream>>>(Qw, Ksw, Vsw, Ow);

  out_k<<<dim3(M / 128, DMODEL / 64), 256, 0, stream>>>(Ow, Wt + 3 * WT, bo, out);
}